// Round 7
// baseline (661.922 us; speedup 1.0000x reference)
//
#include <hip/hip_runtime.h>
#include <math.h>

#define PI_LEN 0.3141592653589793f   // pi / 10.0
#define LEN_F  10.0f
#define TBL    4096                   // table rows = TBL+1

__device__ __forceinline__ float fsilu(float x) {
  return x * __builtin_amdgcn_rcpf(1.f + __expf(-x));
}

// ---------------------------------------------------------------------------
// hist: deg[dst]++
// ---------------------------------------------------------------------------
__global__ __launch_bounds__(256) void hist_kernel(const int* __restrict__ ei,
                                                   int* __restrict__ deg, int E_) {
  int e = blockIdx.x * 256 + threadIdx.x;
  if (e < E_) atomicAdd(&deg[ei[E_ + e]], 1);
}

// ---------------------------------------------------------------------------
// tbl role helper (32 t-rows / 1024-thread block; half-wave-private LDS rows
// -> no barriers; wave lockstep + lgkmcnt orders ds ops)
// ---------------------------------------------------------------------------
__device__ __forceinline__ void tbl_role(
    int i, int g, int t,
    const float* __restrict__ w1, const float* __restrict__ b1,
    const float* __restrict__ w2, const float* __restrict__ b2,
    float4* __restrict__ tbl4, float (*pe)[32], float (*hl)[32])
{
  bool okt = (t <= TBL);
  float d = (float)t * (LEN_F / (float)TBL);
  pe[i][g] = (g < 16) ? __sinf(d * (float)(g + 1) * PI_LEN)
                      : __cosf(d * (float)(g - 15) * PI_LEN);
  float h = b1[g];
  for (int k = 0; k < 32; ++k) h += pe[i][k] * w1[k*32 + g];
  hl[i][g] = fsilu(h);
  float o0 = b2[g], o1 = b2[32+g], o2 = b2[64+g], o3 = b2[96+g];
  for (int k = 0; k < 32; ++k) {
    float hk = hl[i][k];
    o0 += hk * w2[k*128 +      g];
    o1 += hk * w2[k*128 + 32 + g];
    o2 += hk * w2[k*128 + 64 + g];
    o3 += hk * w2[k*128 + 96 + g];
  }
  if (okt) tbl4[(long)t*32 + g] = make_float4(o0, o1, o2, o3);
}

// ---------------------------------------------------------------------------
// scan + prep roles in ONE launch (block roles, all independent of scan):
//   block 0                      -> exclusive scan of deg -> off, cursor
//   [1, 1+nodeB32)               -> nodeA(l0): Aout4a from s_in
//   next tblB32                  -> filter table l0
//   next tblB32                  -> filter table l1
// Aout4[n*32+g] = (gates, cpg, sed, sf * s[n][g])
// ---------------------------------------------------------------------------
__global__ __launch_bounds__(1024) void scan_prep_kernel(
    const int* __restrict__ deg, int* __restrict__ off,
    int* __restrict__ cursor, int N_,
    const float* __restrict__ s,
    const float* __restrict__ mpw1, const float* __restrict__ mpb1,
    const float* __restrict__ mpw2, const float* __restrict__ mpb2,
    const float* __restrict__ mww1a, const float* __restrict__ mwb1a,
    const float* __restrict__ mww2a, const float* __restrict__ mwb2a,
    const float* __restrict__ mww1b, const float* __restrict__ mwb1b,
    const float* __restrict__ mww2b, const float* __restrict__ mwb2b,
    float4* __restrict__ Aout4a, float4* __restrict__ tbl4a,
    float4* __restrict__ tbl4b, int nodeB32, int tblB32)
{
  __shared__ float xs[32][32];
  __shared__ float hs[32][32];
  __shared__ int wtot[16];
  __shared__ int carry_s;
  int bid = blockIdx.x;
  int tid = threadIdx.x;
  if (bid == 0) {                            // ---- scan role ----
    int lane = tid & 63, wid = tid >> 6;
    if (tid == 0) carry_s = 0;
    __syncthreads();
    int nch = (N_ + 8191) / 8192;
    for (int c = 0; c < nch; ++c) {
      int base_idx = c * 8192 + tid * 8;
      int x[8]; int mysum = 0;
      #pragma unroll
      for (int j = 0; j < 8; ++j) { int idx = base_idx + j; x[j] = (idx < N_) ? deg[idx] : 0; mysum += x[j]; }
      int incl = mysum;
      #pragma unroll
      for (int st = 1; st < 64; st <<= 1) { int t = __shfl_up(incl, st, 64); if (lane >= st) incl += t; }
      if (lane == 63) wtot[wid] = incl;
      __syncthreads();
      if (wid == 0) {
        int wt = (lane < 16) ? wtot[lane] : 0;
        #pragma unroll
        for (int st = 1; st < 16; st <<= 1) { int t = __shfl_up(wt, st, 64); if (lane >= st) wt += t; }
        if (lane < 16) wtot[lane] = wt;
      }
      __syncthreads();
      int wexcl = (wid > 0) ? wtot[wid - 1] : 0;
      int run = carry_s + wexcl + (incl - mysum);
      #pragma unroll
      for (int j = 0; j < 8; ++j) {
        int idx = base_idx + j;
        if (idx < N_) { off[idx] = run; cursor[idx] = run; }
        run += x[j];
      }
      __syncthreads();
      if (tid == 0) carry_s += wtot[15];
      __syncthreads();
    }
    if (tid == 0) off[N_] = carry_s;
    return;
  }
  bid -= 1;
  int i = tid >> 5, g = tid & 31;
  if (bid < nodeB32) {                       // ---- nodeA(l0) role ----
    long n = (long)bid * 32 + i;
    bool ok = (n < N_);
    xs[i][g] = ok ? s[n*32 + g] : 0.f;
    float h = mpb1[g];
    for (int k = 0; k < 32; ++k) h += xs[i][k] * mpw1[k*32 + g];
    hs[i][g] = fsilu(h);
    float o0 = mpb2[g], o1 = mpb2[32+g], o2 = mpb2[64+g], o3 = mpb2[96+g];
    for (int k = 0; k < 32; ++k) {
      float hk = hs[i][k];
      o0 += hk * mpw2[k*128 +      g];
      o1 += hk * mpw2[k*128 + 32 + g];
      o2 += hk * mpw2[k*128 + 64 + g];
      o3 += hk * mpw2[k*128 + 96 + g];
    }
    if (ok) Aout4a[n*32 + g] = make_float4(o0, o1, o2, o3 * xs[i][g]);
    return;
  }
  bid -= nodeB32;
  if (bid < tblB32) {                        // ---- tbl l0 role ----
    tbl_role(i, g, bid * 32 + i, mww1a, mwb1a, mww2a, mwb2a, tbl4a, xs, hs);
    return;
  }
  bid -= tblB32;                             // ---- tbl l1 role ----
  tbl_role(i, g, bid * 32 + i, mww1b, mwb1b, mww2b, mwb2b, tbl4b, xs, hs);
}

// ---------------------------------------------------------------------------
// scatter: CSR data perm (after scan)
// ---------------------------------------------------------------------------
__global__ __launch_bounds__(256) void scatter_kernel(
    const int* __restrict__ ei, const float* __restrict__ dist,
    const float* __restrict__ edir, int* __restrict__ cursor,
    int* __restrict__ srcp, float4* __restrict__ edata, int E_) {
  int e = blockIdx.x * 256 + threadIdx.x;
  if (e < E_) {
    int dst = ei[E_ + e];
    int pos = atomicAdd(&cursor[dst], 1);
    srcp[pos] = ei[e];
    edata[pos] = make_float4(edir[3*e], edir[3*e+1], edir[3*e+2], dist[e]);
  }
}

// ---------------------------------------------------------------------------
// gather loop core (r4-proven shape): 4 edges per half-wave batched.
// ---------------------------------------------------------------------------
#define EDGE_MATH(ED, M0, M1, FR, Av, V0, V1, V2)                         \
  {                                                                        \
    float ga = M0.x + FR*(M1.x - M0.x);                                    \
    float ca = M0.y + FR*(M1.y - M0.y);                                    \
    float da = M0.z + FR*(M1.z - M0.z);                                    \
    float sa = M0.w + FR*(M1.w - M0.w);                                    \
    float gates = ga*Av.x, cpg = ca*Av.y, sed = da*Av.z;                   \
    acc_s += sa*Av.w;                                                      \
    float crx = ED.y*vd2 - ED.z*vd1;                                       \
    float cry = ED.z*vd0 - ED.x*vd2;                                       \
    float crz = ED.x*vd1 - ED.y*vd0;                                       \
    av0 += sed*ED.x + gates*V0 + cpg*crx;                                  \
    av1 += sed*ED.y + gates*V1 + cpg*cry;                                  \
    av2 += sed*ED.z + gates*V2 + cpg*crz;                                  \
  }

#define GATHER_LOOP(VPREV, TBL4, AOUT4)                                    \
  int deg = pend - pstart;                                                 \
  int nfull = deg >> 3;                                                    \
  int pb = pstart + hf * 4;                                                \
  for (int it = 0; it < nfull; ++it, pb += 8) {                            \
    int srcs[4]; float4 ed[4];                                             \
    _Pragma("unroll")                                                      \
    for (int b = 0; b < 4; ++b) { srcs[b] = srcp[pb + b]; ed[b] = edata[pb + b]; } \
    float4 m0[4], m1[4], A[4]; float fr[4];                                \
    float vs0[4], vs1[4], vs2[4];                                          \
    _Pragma("unroll")                                                      \
    for (int b = 0; b < 4; ++b) {                                          \
      float x = ed[b].w * inv_step;                                        \
      float f = floorf(x);                                                 \
      int i0 = (int)f; if (i0 > TBL - 1) i0 = TBL - 1;                     \
      fr[b] = x - f;                                                       \
      m0[b] = TBL4[(long)i0*32 + g];                                       \
      m1[b] = TBL4[(long)(i0 + 1)*32 + g];                                 \
      A[b]  = AOUT4[(long)srcs[b]*32 + g];                                 \
      const float* vq = VPREV + (long)srcs[b]*96 + g*3;                    \
      vs0[b] = vq[0]; vs1[b] = vq[1]; vs2[b] = vq[2];                      \
    }                                                                      \
    _Pragma("unroll")                                                      \
    for (int b = 0; b < 4; ++b)                                            \
      EDGE_MATH(ed[b], m0[b], m1[b], fr[b], A[b], vs0[b], vs1[b], vs2[b]); \
  }                                                                        \
  int p = pstart + nfull * 8 + hf;                                         \
  for (; p + 2 < pend; p += 4) {                                           \
    int  s0_ = srcp[p], s1_ = srcp[p + 2];                                 \
    float4 e0 = edata[p], e1 = edata[p + 2];                               \
    float x0 = e0.w * inv_step, x1 = e1.w * inv_step;                      \
    float f0 = floorf(x0), f1 = floorf(x1);                                \
    int i0 = (int)f0; if (i0 > TBL - 1) i0 = TBL - 1;                      \
    int i1 = (int)f1; if (i1 > TBL - 1) i1 = TBL - 1;                      \
    float r0 = x0 - f0, r1 = x1 - f1;                                      \
    float4 a0 = TBL4[(long)i0*32 + g], b0 = TBL4[(long)(i0+1)*32 + g];     \
    float4 a1 = TBL4[(long)i1*32 + g], b1 = TBL4[(long)(i1+1)*32 + g];     \
    float4 A0 = AOUT4[(long)s0_*32 + g], A1 = AOUT4[(long)s1_*32 + g];     \
    const float* vq0 = VPREV + (long)s0_*96 + g*3;                         \
    const float* vq1 = VPREV + (long)s1_*96 + g*3;                         \
    float u0 = vq0[0], u1 = vq0[1], u2 = vq0[2];                           \
    float t0 = vq1[0], t1 = vq1[1], t2 = vq1[2];                           \
    EDGE_MATH(e0, a0, b0, r0, A0, u0, u1, u2);                             \
    EDGE_MATH(e1, a1, b1, r1, A1, t0, t1, t2);                             \
  }                                                                        \
  if (p < pend) {                                                          \
    int  s0_ = srcp[p];                                                    \
    float4 e0 = edata[p];                                                  \
    float x0 = e0.w * inv_step;                                            \
    float f0 = floorf(x0);                                                 \
    int i0 = (int)f0; if (i0 > TBL - 1) i0 = TBL - 1;                      \
    float r0 = x0 - f0;                                                    \
    float4 a0 = TBL4[(long)i0*32 + g], b0 = TBL4[(long)(i0+1)*32 + g];     \
    float4 A0 = AOUT4[(long)s0_*32 + g];                                   \
    const float* vq0 = VPREV + (long)s0_*96 + g*3;                         \
    float u0 = vq0[0], u1 = vq0[1], u2 = vq0[2];                           \
    EDGE_MATH(e0, a0, b0, r0, A0, u0, u1, u2);                             \
  }                                                                        \
  av0   += __shfl_xor(av0, 32);                                            \
  av1   += __shfl_xor(av1, 32);                                            \
  av2   += __shfl_xor(av2, 32);                                            \
  acc_s += __shfl_xor(acc_s, 32);

// ---------------------------------------------------------------------------
// gather_mid: gather(l0) + update(l0) + nodeA(l1), one wave64 per node,
// barrier-free (per-wave LDS rows; both halves compute update redundantly,
// hf==0 lanes write). Writes sB, vB, Aout4b.
// ---------------------------------------------------------------------------
__global__ __launch_bounds__(256) void gather_mid_kernel(
    const int* __restrict__ off, const int* __restrict__ srcp,
    const float4* __restrict__ edata, const float4* __restrict__ tbl4,
    const float* __restrict__ s_prev, const float* __restrict__ v_prev,
    const float4* __restrict__ Aout4,
    const float* __restrict__ uU, const float* __restrict__ uV,
    const float* __restrict__ uw1, const float* __restrict__ ub1,
    const float* __restrict__ uw2, const float* __restrict__ ub2,
    const float* __restrict__ nw1, const float* __restrict__ nb1,
    const float* __restrict__ nw2, const float* __restrict__ nb2,
    float* __restrict__ s_out, float* __restrict__ v_out,
    float4* __restrict__ Aout4b, int N_)
{
  __shared__ float vld[4][96];
  __shared__ float in64[4][64];
  __shared__ float hld[4][32];
  int tid = threadIdx.x, w = tid >> 6, lane = tid & 63, g = lane & 31, hf = lane >> 5;
  int n = blockIdx.x * 4 + w;
  if (n >= N_) return;
  const float* vp = v_prev + (long)n*96 + g*3;
  float vd0 = vp[0], vd1 = vp[1], vd2 = vp[2];
  float s_own = s_prev[(long)n*32 + g];
  int pstart = off[n], pend = off[n + 1];
  float acc_s = 0, av0 = 0, av1 = 0, av2 = 0;
  const float inv_step = (float)TBL / LEN_F;
  GATHER_LOOP(v_prev, tbl4, Aout4)

  // ---- update(l0), per-wave, barrier-free ----
  float nv0 = vd0 + av0, nv1 = vd1 + av1, nv2 = vd2 + av2;
  float ns  = s_own + acc_s;
  if (hf == 0) { vld[w][g*3+0] = nv0; vld[w][g*3+1] = nv1; vld[w][g*3+2] = nv2; }
  float Vv0=0,Vv1=0,Vv2=0,Uv0=0,Uv1=0,Uv2=0;
  for (int f = 0; f < 32; ++f) {
    float wu = uU[f*32 + g];
    float wv = uV[f*32 + g];
    float v0 = vld[w][f*3+0], v1 = vld[w][f*3+1], v2 = vld[w][f*3+2];
    Vv0 += v0*wv; Vv1 += v1*wv; Vv2 += v2*wv;
    Uv0 += v0*wu; Uv1 += v1*wu; Uv2 += v2*wu;
  }
  float Vn = sqrtf(Vv0*Vv0 + Vv1*Vv1 + Vv2*Vv2);
  if (hf == 0) { in64[w][g] = Vn; in64[w][32 + g] = ns; }
  float h = ub1[g];
  for (int k = 0; k < 64; ++k) h += in64[w][k] * uw1[k*32 + g];
  h = fsilu(h);
  if (hf == 0) hld[w][g] = h;
  float og = ub2[g], ossn = ub2[32 + g], oadd = ub2[64 + g];
  for (int k = 0; k < 32; ++k) {
    float hk = hld[w][k];
    og   += hk * uw2[k*96 +      g];
    ossn += hk * uw2[k*96 + 32 + g];
    oadd += hk * uw2[k*96 + 64 + g];
  }
  float s_fin = ns + Vn*Vn*ossn + oadd;
  if (hf == 0) {
    float* vo = v_out + (long)n*96 + g*3;
    vo[0] = nv0 + og*Uv0;
    vo[1] = nv1 + og*Uv1;
    vo[2] = nv2 + og*Uv2;
    s_out[(long)n*32 + g] = s_fin;
  }
  // ---- nodeA(l1) from s_fin ----
  if (hf == 0) in64[w][g] = s_fin;
  float h2 = nb1[g];
  for (int k = 0; k < 32; ++k) h2 += in64[w][k] * nw1[k*32 + g];
  h2 = fsilu(h2);
  if (hf == 0) hld[w][g] = h2;
  float o0 = nb2[g], o1 = nb2[32+g], o2 = nb2[64+g], o3 = nb2[96+g];
  for (int k = 0; k < 32; ++k) {
    float hk = hld[w][k];
    o0 += hk * nw2[k*128 +      g];
    o1 += hk * nw2[k*128 + 32 + g];
    o2 += hk * nw2[k*128 + 64 + g];
    o3 += hk * nw2[k*128 + 96 + g];
  }
  if (hf == 0) Aout4b[(long)n*32 + g] = make_float4(o0, o1, o2, o3 * s_fin);
}

// ---------------------------------------------------------------------------
// gather_fin: gather(l1) + update(l1) + readout. Writes d_out only.
// ---------------------------------------------------------------------------
__global__ __launch_bounds__(256) void gather_fin_kernel(
    const int* __restrict__ off, const int* __restrict__ srcp,
    const float4* __restrict__ edata, const float4* __restrict__ tbl4,
    const float* __restrict__ s_prev, const float* __restrict__ v_prev,
    const float4* __restrict__ Aout4,
    const float* __restrict__ uU, const float* __restrict__ uV,
    const float* __restrict__ uw1, const float* __restrict__ ub1,
    const float* __restrict__ uw2, const float* __restrict__ ub2,
    const float* __restrict__ rw1, const float* __restrict__ rb1,
    const float* __restrict__ rw2, const float* __restrict__ rb2,
    const float* __restrict__ roV, float* __restrict__ out, int N_)
{
  __shared__ float vld[4][96];
  __shared__ float in64[4][64];
  __shared__ float hld[4][32];
  int tid = threadIdx.x, w = tid >> 6, lane = tid & 63, g = lane & 31, hf = lane >> 5;
  int n = blockIdx.x * 4 + w;
  if (n >= N_) return;
  const float* vp = v_prev + (long)n*96 + g*3;
  float vd0 = vp[0], vd1 = vp[1], vd2 = vp[2];
  float s_own = s_prev[(long)n*32 + g];
  int pstart = off[n], pend = off[n + 1];
  float acc_s = 0, av0 = 0, av1 = 0, av2 = 0;
  const float inv_step = (float)TBL / LEN_F;
  GATHER_LOOP(v_prev, tbl4, Aout4)

  // ---- update(l1) ----
  float nv0 = vd0 + av0, nv1 = vd1 + av1, nv2 = vd2 + av2;
  float ns  = s_own + acc_s;
  if (hf == 0) { vld[w][g*3+0] = nv0; vld[w][g*3+1] = nv1; vld[w][g*3+2] = nv2; }
  float Vv0=0,Vv1=0,Vv2=0,Uv0=0,Uv1=0,Uv2=0;
  for (int f = 0; f < 32; ++f) {
    float wu = uU[f*32 + g];
    float wv = uV[f*32 + g];
    float v0 = vld[w][f*3+0], v1 = vld[w][f*3+1], v2 = vld[w][f*3+2];
    Vv0 += v0*wv; Vv1 += v1*wv; Vv2 += v2*wv;
    Uv0 += v0*wu; Uv1 += v1*wu; Uv2 += v2*wu;
  }
  float Vn = sqrtf(Vv0*Vv0 + Vv1*Vv1 + Vv2*Vv2);
  if (hf == 0) { in64[w][g] = Vn; in64[w][32 + g] = ns; }
  float h = ub1[g];
  for (int k = 0; k < 64; ++k) h += in64[w][k] * uw1[k*32 + g];
  h = fsilu(h);
  if (hf == 0) hld[w][g] = h;
  float og = ub2[g], ossn = ub2[32 + g], oadd = ub2[64 + g];
  for (int k = 0; k < 32; ++k) {
    float hk = hld[w][k];
    og   += hk * uw2[k*96 +      g];
    ossn += hk * uw2[k*96 + 32 + g];
    oadd += hk * uw2[k*96 + 64 + g];
  }
  float s_fin = ns + Vn*Vn*ossn + oadd;
  float vf0 = nv0 + og*Uv0, vf1 = nv1 + og*Uv1, vf2 = nv2 + og*Uv2;
  // ---- readout ----
  if (hf == 0) in64[w][g] = s_fin;
  float h2 = rb1[g];
  for (int k = 0; k < 32; ++k) h2 += in64[w][k] * rw1[k*32 + g];
  h2 = fsilu(h2);
  if (hf == 0) hld[w][g] = h2;
  float inv = rb2[g], gate = rb2[32 + g];
  for (int k = 0; k < 32; ++k) {
    float hk = hld[w][k];
    inv  += hk * rw2[k*64 +      g];
    gate += hk * rw2[k*64 + 32 + g];
  }
  if (hf == 0) { vld[w][g*3+0] = vf0; vld[w][g*3+1] = vf1; vld[w][g*3+2] = vf2; }
  float R0 = 0, R1 = 0, R2 = 0;
  for (int f = 0; f < 32; ++f) {
    float wv = roV[f*32 + g];
    R0 += vld[w][f*3+0]*wv; R1 += vld[w][f*3+1]*wv; R2 += vld[w][f*3+2]*wv;
  }
  if (hf == 0) {
    out[(long)n*32 + g] = inv;
    long eb = (long)N_*32 + (long)n*96 + (long)g*3;
    out[eb+0] = gate*R0; out[eb+1] = gate*R1; out[eb+2] = gate*R2;
  }
}

// ---------------------------------------------------------------------------
extern "C" void kernel_launch(void* const* d_in, const int* in_sizes, int n_in,
                              void* d_out, int out_size, void* d_ws, size_t ws_size,
                              hipStream_t stream)
{
  const float* s_in  = (const float*)d_in[0];
  const float* v_in  = (const float*)d_in[1];   // (N, F, 3)
  const int*   ei    = (const int*)  d_in[2];
  const float* dist  = (const float*)d_in[3];
  const float* edir  = (const float*)d_in[4];
  const float* mp_w1 = (const float*)d_in[5];
  const float* mp_b1 = (const float*)d_in[6];
  const float* mp_w2 = (const float*)d_in[7];
  const float* mp_b2 = (const float*)d_in[8];
  const float* mw_w1 = (const float*)d_in[9];
  const float* mw_b1 = (const float*)d_in[10];
  const float* mw_w2 = (const float*)d_in[11];
  const float* mw_b2 = (const float*)d_in[12];
  const float* u_U   = (const float*)d_in[13];
  const float* u_V   = (const float*)d_in[14];
  const float* u_w1  = (const float*)d_in[15];
  const float* u_b1  = (const float*)d_in[16];
  const float* u_w2  = (const float*)d_in[17];
  const float* u_b2  = (const float*)d_in[18];
  const float* ro_w1 = (const float*)d_in[19];
  const float* ro_b1 = (const float*)d_in[20];
  const float* ro_w2 = (const float*)d_in[21];
  const float* ro_b2 = (const float*)d_in[22];
  const float* ro_V  = (const float*)d_in[23];

  int N_ = in_sizes[0] / 32;
  int E_ = in_sizes[3];

  float*  sB    = (float*)d_ws;                       // N*32
  float*  vB    = sB + (size_t)N_*32;                 // N*96
  float4* Aout4a= (float4*)(vB + (size_t)N_*96);      // N*32 float4
  float4* Aout4b= Aout4a + (size_t)N_*32;             // N*32 float4
  float4* tbl4a = Aout4b + (size_t)N_*32;             // (TBL+1)*32 float4
  float4* tbl4b = tbl4a + (size_t)(TBL+1)*32;         // (TBL+1)*32 float4
  float4* edata = tbl4b + (size_t)(TBL+1)*32;         // E float4
  int*    srcp  = (int*)(edata + (size_t)E_);         // E
  int*    deg   = srcp + E_;                          // N
  int*    off   = deg + N_;                           // N+1
  int*    cursor= off + N_ + 1;                       // N

  int gathBlocks = (N_ + 3) / 4;
  int edgeBlocks = (E_ + 255) / 256;
  int nodeB32    = (N_ + 31) / 32;
  int tblB32     = (TBL + 1 + 31) / 32;

  // --- CSR hist ---
  hipMemsetAsync(deg, 0, (size_t)N_ * sizeof(int), stream);
  hist_kernel<<<edgeBlocks, 256, 0, stream>>>(ei, deg, E_);

  // --- scan + nodeA(l0) + tbl(l0) + tbl(l1), one launch ---
  scan_prep_kernel<<<1 + nodeB32 + 2*tblB32, 1024, 0, stream>>>(
      deg, off, cursor, N_, s_in,
      mp_w1, mp_b1, mp_w2, mp_b2,
      mw_w1, mw_b1, mw_w2, mw_b2,
      mw_w1 + 1024, mw_b1 + 32, mw_w2 + 4096, mw_b2 + 128,
      Aout4a, tbl4a, tbl4b, nodeB32, tblB32);

  // --- CSR data scatter ---
  scatter_kernel<<<edgeBlocks, 256, 0, stream>>>(ei, dist, edir, cursor, srcp, edata, E_);

  // --- layer 0: gather + update + nodeA(l1) fused ---
  gather_mid_kernel<<<gathBlocks, 256, 0, stream>>>(
      off, srcp, edata, tbl4a, s_in, v_in, Aout4a,
      u_U, u_V, u_w1, u_b1, u_w2, u_b2,
      mp_w1 + 1024, mp_b1 + 32, mp_w2 + 4096, mp_b2 + 128,
      sB, vB, Aout4b, N_);

  // --- layer 1: gather + update + readout fused ---
  gather_fin_kernel<<<gathBlocks, 256, 0, stream>>>(
      off, srcp, edata, tbl4b, sB, vB, Aout4b,
      u_U + 1024, u_V + 1024, u_w1 + 2048, u_b1 + 32, u_w2 + 3072, u_b2 + 96,
      ro_w1, ro_b1, ro_w2, ro_b2, ro_V, (float*)d_out, N_);
}

// Round 8
// 611.310 us; speedup vs baseline: 1.0828x; 1.0828x over previous
//
#include <hip/hip_runtime.h>
#include <math.h>

#define PI_LEN 0.3141592653589793f   // pi / 10.0
#define LEN_F  10.0f
#define TBL    4096                   // table rows = TBL+1

__device__ __forceinline__ float fsilu(float x) {
  return x * __builtin_amdgcn_rcpf(1.f + __expf(-x));
}

// ---------------------------------------------------------------------------
// hist: deg[dst]++
// ---------------------------------------------------------------------------
__global__ __launch_bounds__(256) void hist_kernel(const int* __restrict__ ei,
                                                   int* __restrict__ deg, int E_) {
  int e = blockIdx.x * 256 + threadIdx.x;
  if (e < E_) atomicAdd(&deg[ei[E_ + e]], 1);
}

// ---------------------------------------------------------------------------
// tbl role helper (32 t-rows / 1024-thread block; half-wave-private LDS rows)
// ---------------------------------------------------------------------------
__device__ __forceinline__ void tbl_role(
    int i, int g, int t,
    const float* __restrict__ w1, const float* __restrict__ b1,
    const float* __restrict__ w2, const float* __restrict__ b2,
    float4* __restrict__ tbl4, float (*pe)[32], float (*hl)[32])
{
  bool okt = (t <= TBL);
  float d = (float)t * (LEN_F / (float)TBL);
  pe[i][g] = (g < 16) ? __sinf(d * (float)(g + 1) * PI_LEN)
                      : __cosf(d * (float)(g - 15) * PI_LEN);
  float h = b1[g];
  for (int k = 0; k < 32; ++k) h += pe[i][k] * w1[k*32 + g];
  hl[i][g] = fsilu(h);
  float o0 = b2[g], o1 = b2[32+g], o2 = b2[64+g], o3 = b2[96+g];
  for (int k = 0; k < 32; ++k) {
    float hk = hl[i][k];
    o0 += hk * w2[k*128 +      g];
    o1 += hk * w2[k*128 + 32 + g];
    o2 += hk * w2[k*128 + 64 + g];
    o3 += hk * w2[k*128 + 96 + g];
  }
  if (okt) tbl4[(long)t*32 + g] = make_float4(o0, o1, o2, o3);
}

// ---------------------------------------------------------------------------
// scan + prep roles in ONE launch:
//   block 0       -> exclusive scan of deg -> off, cursor
//   next nodeB32  -> nodeA(l0): Aout4a from s_in
//   next tblB32   -> filter table l0
//   next tblB32   -> filter table l1
// ---------------------------------------------------------------------------
__global__ __launch_bounds__(1024) void scan_prep_kernel(
    const int* __restrict__ deg, int* __restrict__ off,
    int* __restrict__ cursor, int N_,
    const float* __restrict__ s,
    const float* __restrict__ mpw1, const float* __restrict__ mpb1,
    const float* __restrict__ mpw2, const float* __restrict__ mpb2,
    const float* __restrict__ mww1a, const float* __restrict__ mwb1a,
    const float* __restrict__ mww2a, const float* __restrict__ mwb2a,
    const float* __restrict__ mww1b, const float* __restrict__ mwb1b,
    const float* __restrict__ mww2b, const float* __restrict__ mwb2b,
    float4* __restrict__ Aout4a, float4* __restrict__ tbl4a,
    float4* __restrict__ tbl4b, int nodeB32, int tblB32)
{
  __shared__ float xs[32][32];
  __shared__ float hs[32][32];
  __shared__ int wtot[16];
  __shared__ int carry_s;
  int bid = blockIdx.x;
  int tid = threadIdx.x;
  if (bid == 0) {                            // ---- scan role ----
    int lane = tid & 63, wid = tid >> 6;
    if (tid == 0) carry_s = 0;
    __syncthreads();
    int nch = (N_ + 8191) / 8192;
    for (int c = 0; c < nch; ++c) {
      int base_idx = c * 8192 + tid * 8;
      int x[8]; int mysum = 0;
      #pragma unroll
      for (int j = 0; j < 8; ++j) { int idx = base_idx + j; x[j] = (idx < N_) ? deg[idx] : 0; mysum += x[j]; }
      int incl = mysum;
      #pragma unroll
      for (int st = 1; st < 64; st <<= 1) { int t = __shfl_up(incl, st, 64); if (lane >= st) incl += t; }
      if (lane == 63) wtot[wid] = incl;
      __syncthreads();
      if (wid == 0) {
        int wt = (lane < 16) ? wtot[lane] : 0;
        #pragma unroll
        for (int st = 1; st < 16; st <<= 1) { int t = __shfl_up(wt, st, 64); if (lane >= st) wt += t; }
        if (lane < 16) wtot[lane] = wt;
      }
      __syncthreads();
      int wexcl = (wid > 0) ? wtot[wid - 1] : 0;
      int run = carry_s + wexcl + (incl - mysum);
      #pragma unroll
      for (int j = 0; j < 8; ++j) {
        int idx = base_idx + j;
        if (idx < N_) { off[idx] = run; cursor[idx] = run; }
        run += x[j];
      }
      __syncthreads();
      if (tid == 0) carry_s += wtot[15];
      __syncthreads();
    }
    if (tid == 0) off[N_] = carry_s;
    return;
  }
  bid -= 1;
  int i = tid >> 5, g = tid & 31;
  if (bid < nodeB32) {                       // ---- nodeA(l0) role ----
    long n = (long)bid * 32 + i;
    bool ok = (n < N_);
    xs[i][g] = ok ? s[n*32 + g] : 0.f;
    float h = mpb1[g];
    for (int k = 0; k < 32; ++k) h += xs[i][k] * mpw1[k*32 + g];
    hs[i][g] = fsilu(h);
    float o0 = mpb2[g], o1 = mpb2[32+g], o2 = mpb2[64+g], o3 = mpb2[96+g];
    for (int k = 0; k < 32; ++k) {
      float hk = hs[i][k];
      o0 += hk * mpw2[k*128 +      g];
      o1 += hk * mpw2[k*128 + 32 + g];
      o2 += hk * mpw2[k*128 + 64 + g];
      o3 += hk * mpw2[k*128 + 96 + g];
    }
    if (ok) Aout4a[n*32 + g] = make_float4(o0, o1, o2, o3 * xs[i][g]);
    return;
  }
  bid -= nodeB32;
  if (bid < tblB32) {                        // ---- tbl l0 role ----
    tbl_role(i, g, bid * 32 + i, mww1a, mwb1a, mww2a, mwb2a, tbl4a, xs, hs);
    return;
  }
  bid -= tblB32;                             // ---- tbl l1 role ----
  tbl_role(i, g, bid * 32 + i, mww1b, mwb1b, mww2b, mwb2b, tbl4b, xs, hs);
}

// ---------------------------------------------------------------------------
// scatter: CSR data perm (after scan)
// ---------------------------------------------------------------------------
__global__ __launch_bounds__(256) void scatter_kernel(
    const int* __restrict__ ei, const float* __restrict__ dist,
    const float* __restrict__ edir, int* __restrict__ cursor,
    int* __restrict__ srcp, float4* __restrict__ edata, int E_) {
  int e = blockIdx.x * 256 + threadIdx.x;
  if (e < E_) {
    int dst = ei[E_ + e];
    int pos = atomicAdd(&cursor[dst], 1);
    srcp[pos] = ei[e];
    edata[pos] = make_float4(edir[3*e], edir[3*e+1], edir[3*e+2], dist[e]);
  }
}

// ---------------------------------------------------------------------------
// gather: EXACT round-4 proven shape (56 VGPR, no LDS, no barriers).
// 4 nodes/block, one wave64/node, 4 edges per half-wave batched.
// Writes acc4[n*32+g] = (av0, av1, av2, acc_s).
// ---------------------------------------------------------------------------
#define EDGE_MATH(ED, M0, M1, FR, Av, V0, V1, V2)                         \
  {                                                                        \
    float ga = M0.x + FR*(M1.x - M0.x);                                    \
    float ca = M0.y + FR*(M1.y - M0.y);                                    \
    float da = M0.z + FR*(M1.z - M0.z);                                    \
    float sa = M0.w + FR*(M1.w - M0.w);                                    \
    float gates = ga*Av.x, cpg = ca*Av.y, sed = da*Av.z;                   \
    acc_s += sa*Av.w;                                                      \
    float crx = ED.y*vd2 - ED.z*vd1;                                       \
    float cry = ED.z*vd0 - ED.x*vd2;                                       \
    float crz = ED.x*vd1 - ED.y*vd0;                                       \
    av0 += sed*ED.x + gates*V0 + cpg*crx;                                  \
    av1 += sed*ED.y + gates*V1 + cpg*cry;                                  \
    av2 += sed*ED.z + gates*V2 + cpg*crz;                                  \
  }

__global__ __launch_bounds__(256) void gather_kernel(
    const int* __restrict__ off, const int* __restrict__ srcp,
    const float4* __restrict__ edata, const float4* __restrict__ tbl4,
    const float* __restrict__ v_prev, const float4* __restrict__ Aout4,
    float4* __restrict__ acc4, int N_)
{
  int tid = threadIdx.x, w = tid >> 6, lane = tid & 63, g = lane & 31, hf = lane >> 5;
  int n = blockIdx.x * 4 + w;
  if (n >= N_) return;
  const float* vp = v_prev + (long)n*96 + g*3;
  float vd0 = vp[0], vd1 = vp[1], vd2 = vp[2];
  int pstart = off[n], pend = off[n + 1];
  float acc_s = 0, av0 = 0, av1 = 0, av2 = 0;
  const float inv_step = (float)TBL / LEN_F;

  int deg = pend - pstart;
  int nfull = deg >> 3;
  int pb = pstart + hf * 4;
  for (int it = 0; it < nfull; ++it, pb += 8) {
    int srcs[4]; float4 ed[4];
    #pragma unroll
    for (int b = 0; b < 4; ++b) { srcs[b] = srcp[pb + b]; ed[b] = edata[pb + b]; }
    float4 m0[4], m1[4], A[4]; float fr[4];
    float vs0[4], vs1[4], vs2[4];
    #pragma unroll
    for (int b = 0; b < 4; ++b) {
      float x = ed[b].w * inv_step;
      float f = floorf(x);
      int i0 = (int)f; if (i0 > TBL - 1) i0 = TBL - 1;
      fr[b] = x - f;
      m0[b] = tbl4[(long)i0*32 + g];
      m1[b] = tbl4[(long)(i0 + 1)*32 + g];
      A[b]  = Aout4[(long)srcs[b]*32 + g];
      const float* vq = v_prev + (long)srcs[b]*96 + g*3;
      vs0[b] = vq[0]; vs1[b] = vq[1]; vs2[b] = vq[2];
    }
    #pragma unroll
    for (int b = 0; b < 4; ++b)
      EDGE_MATH(ed[b], m0[b], m1[b], fr[b], A[b], vs0[b], vs1[b], vs2[b]);
  }
  int p = pstart + nfull * 8 + hf;
  for (; p + 2 < pend; p += 4) {
    int  s0_ = srcp[p], s1_ = srcp[p + 2];
    float4 e0 = edata[p], e1 = edata[p + 2];
    float x0 = e0.w * inv_step, x1 = e1.w * inv_step;
    float f0 = floorf(x0), f1 = floorf(x1);
    int i0 = (int)f0; if (i0 > TBL - 1) i0 = TBL - 1;
    int i1 = (int)f1; if (i1 > TBL - 1) i1 = TBL - 1;
    float r0 = x0 - f0, r1 = x1 - f1;
    float4 a0 = tbl4[(long)i0*32 + g], b0 = tbl4[(long)(i0+1)*32 + g];
    float4 a1 = tbl4[(long)i1*32 + g], b1 = tbl4[(long)(i1+1)*32 + g];
    float4 A0 = Aout4[(long)s0_*32 + g], A1 = Aout4[(long)s1_*32 + g];
    const float* vq0 = v_prev + (long)s0_*96 + g*3;
    const float* vq1 = v_prev + (long)s1_*96 + g*3;
    float u0 = vq0[0], u1 = vq0[1], u2 = vq0[2];
    float t0 = vq1[0], t1 = vq1[1], t2 = vq1[2];
    EDGE_MATH(e0, a0, b0, r0, A0, u0, u1, u2);
    EDGE_MATH(e1, a1, b1, r1, A1, t0, t1, t2);
  }
  if (p < pend) {
    int  s0_ = srcp[p];
    float4 e0 = edata[p];
    float x0 = e0.w * inv_step;
    float f0 = floorf(x0);
    int i0 = (int)f0; if (i0 > TBL - 1) i0 = TBL - 1;
    float r0 = x0 - f0;
    float4 a0 = tbl4[(long)i0*32 + g], b0 = tbl4[(long)(i0+1)*32 + g];
    float4 A0 = Aout4[(long)s0_*32 + g];
    const float* vq0 = v_prev + (long)s0_*96 + g*3;
    float u0 = vq0[0], u1 = vq0[1], u2 = vq0[2];
    EDGE_MATH(e0, a0, b0, r0, A0, u0, u1, u2);
  }
  av0   += __shfl_xor(av0, 32);
  av1   += __shfl_xor(av1, 32);
  av2   += __shfl_xor(av2, 32);
  acc_s += __shfl_xor(acc_s, 32);
  if (hf == 0) acc4[(long)n*32 + g] = make_float4(av0, av1, av2, acc_s);
}

// ---------------------------------------------------------------------------
// update_mid: update(l0) + nodeA(l1). One wave64/node, 4 nodes/block,
// barrier-free; matvec sums SPLIT across the two halves (16 terms each)
// and combined via shfl_xor(32) -> half the serial chain of r6's version.
// ---------------------------------------------------------------------------
__global__ __launch_bounds__(256) void update_mid_kernel(
    const float* __restrict__ s_prev, const float* __restrict__ v_prev,
    const float4* __restrict__ acc4,
    const float* __restrict__ uU, const float* __restrict__ uV,
    const float* __restrict__ uw1, const float* __restrict__ ub1,
    const float* __restrict__ uw2, const float* __restrict__ ub2,
    const float* __restrict__ nw1, const float* __restrict__ nb1,
    const float* __restrict__ nw2, const float* __restrict__ nb2,
    float* __restrict__ s_out, float* __restrict__ v_out,
    float4* __restrict__ Aout4b, int N_)
{
  __shared__ float vld[4][96];
  __shared__ float in64[4][64];
  __shared__ float hld[4][32];
  int tid = threadIdx.x, w = tid >> 6, lane = tid & 63, g = lane & 31, hf = lane >> 5;
  long n = (long)blockIdx.x * 4 + w;
  if (n >= N_) return;
  float4 a = acc4[n*32 + g];
  const float* vp = v_prev + n*96 + g*3;
  float nv0 = vp[0] + a.x, nv1 = vp[1] + a.y, nv2 = vp[2] + a.z;
  float ns  = s_prev[n*32 + g] + a.w;
  if (hf == 0) { vld[w][g*3+0] = nv0; vld[w][g*3+1] = nv1; vld[w][g*3+2] = nv2; }
  float Vv0=0,Vv1=0,Vv2=0,Uv0=0,Uv1=0,Uv2=0;
  for (int j = 0; j < 16; ++j) {
    int f = hf * 16 + j;
    float wu = uU[f*32 + g];
    float wv = uV[f*32 + g];
    float v0 = vld[w][f*3+0], v1 = vld[w][f*3+1], v2 = vld[w][f*3+2];
    Vv0 += v0*wv; Vv1 += v1*wv; Vv2 += v2*wv;
    Uv0 += v0*wu; Uv1 += v1*wu; Uv2 += v2*wu;
  }
  Vv0 += __shfl_xor(Vv0, 32); Vv1 += __shfl_xor(Vv1, 32); Vv2 += __shfl_xor(Vv2, 32);
  Uv0 += __shfl_xor(Uv0, 32); Uv1 += __shfl_xor(Uv1, 32); Uv2 += __shfl_xor(Uv2, 32);
  float Vn = sqrtf(Vv0*Vv0 + Vv1*Vv1 + Vv2*Vv2);
  if (hf == 0) { in64[w][g] = Vn; in64[w][32 + g] = ns; }
  float h = 0.f;
  for (int j = 0; j < 32; ++j) {
    int k = hf * 32 + j;
    h += in64[w][k] * uw1[k*32 + g];
  }
  h += __shfl_xor(h, 32);
  h = fsilu(h + ub1[g]);
  if (hf == 0) hld[w][g] = h;
  float og = 0.f, ossn = 0.f, oadd = 0.f;
  for (int j = 0; j < 16; ++j) {
    int k = hf * 16 + j;
    float hk = hld[w][k];
    og   += hk * uw2[k*96 +      g];
    ossn += hk * uw2[k*96 + 32 + g];
    oadd += hk * uw2[k*96 + 64 + g];
  }
  og   += __shfl_xor(og, 32);
  ossn += __shfl_xor(ossn, 32);
  oadd += __shfl_xor(oadd, 32);
  og += ub2[g]; ossn += ub2[32 + g]; oadd += ub2[64 + g];
  float s_fin = ns + Vn*Vn*ossn + oadd;
  if (hf == 0) {
    float* vo = v_out + n*96 + g*3;
    vo[0] = nv0 + og*Uv0;
    vo[1] = nv1 + og*Uv1;
    vo[2] = nv2 + og*Uv2;
    s_out[n*32 + g] = s_fin;
  }
  // ---- nodeA(l1) from s_fin ----
  if (hf == 0) in64[w][g] = s_fin;
  float h2 = 0.f;
  for (int j = 0; j < 16; ++j) {
    int k = hf * 16 + j;
    h2 += in64[w][k] * nw1[k*32 + g];
  }
  h2 += __shfl_xor(h2, 32);
  h2 = fsilu(h2 + nb1[g]);
  if (hf == 0) hld[w][g] = h2;
  float o0 = 0.f, o1 = 0.f, o2 = 0.f, o3 = 0.f;
  for (int j = 0; j < 16; ++j) {
    int k = hf * 16 + j;
    float hk = hld[w][k];
    o0 += hk * nw2[k*128 +      g];
    o1 += hk * nw2[k*128 + 32 + g];
    o2 += hk * nw2[k*128 + 64 + g];
    o3 += hk * nw2[k*128 + 96 + g];
  }
  o0 += __shfl_xor(o0, 32); o1 += __shfl_xor(o1, 32);
  o2 += __shfl_xor(o2, 32); o3 += __shfl_xor(o3, 32);
  o0 += nb2[g]; o1 += nb2[32+g]; o2 += nb2[64+g]; o3 += nb2[96+g];
  if (hf == 0) Aout4b[n*32 + g] = make_float4(o0, o1, o2, o3 * s_fin);
}

// ---------------------------------------------------------------------------
// update_fin: update(l1) + readout. Same split-half structure. Writes d_out.
// ---------------------------------------------------------------------------
__global__ __launch_bounds__(256) void update_fin_kernel(
    const float* __restrict__ s_prev, const float* __restrict__ v_prev,
    const float4* __restrict__ acc4,
    const float* __restrict__ uU, const float* __restrict__ uV,
    const float* __restrict__ uw1, const float* __restrict__ ub1,
    const float* __restrict__ uw2, const float* __restrict__ ub2,
    const float* __restrict__ rw1, const float* __restrict__ rb1,
    const float* __restrict__ rw2, const float* __restrict__ rb2,
    const float* __restrict__ roV, float* __restrict__ out, int N_)
{
  __shared__ float vld[4][96];
  __shared__ float in64[4][64];
  __shared__ float hld[4][32];
  int tid = threadIdx.x, w = tid >> 6, lane = tid & 63, g = lane & 31, hf = lane >> 5;
  long n = (long)blockIdx.x * 4 + w;
  if (n >= N_) return;
  float4 a = acc4[n*32 + g];
  const float* vp = v_prev + n*96 + g*3;
  float nv0 = vp[0] + a.x, nv1 = vp[1] + a.y, nv2 = vp[2] + a.z;
  float ns  = s_prev[n*32 + g] + a.w;
  if (hf == 0) { vld[w][g*3+0] = nv0; vld[w][g*3+1] = nv1; vld[w][g*3+2] = nv2; }
  float Vv0=0,Vv1=0,Vv2=0,Uv0=0,Uv1=0,Uv2=0;
  for (int j = 0; j < 16; ++j) {
    int f = hf * 16 + j;
    float wu = uU[f*32 + g];
    float wv = uV[f*32 + g];
    float v0 = vld[w][f*3+0], v1 = vld[w][f*3+1], v2 = vld[w][f*3+2];
    Vv0 += v0*wv; Vv1 += v1*wv; Vv2 += v2*wv;
    Uv0 += v0*wu; Uv1 += v1*wu; Uv2 += v2*wu;
  }
  Vv0 += __shfl_xor(Vv0, 32); Vv1 += __shfl_xor(Vv1, 32); Vv2 += __shfl_xor(Vv2, 32);
  Uv0 += __shfl_xor(Uv0, 32); Uv1 += __shfl_xor(Uv1, 32); Uv2 += __shfl_xor(Uv2, 32);
  float Vn = sqrtf(Vv0*Vv0 + Vv1*Vv1 + Vv2*Vv2);
  if (hf == 0) { in64[w][g] = Vn; in64[w][32 + g] = ns; }
  float h = 0.f;
  for (int j = 0; j < 32; ++j) {
    int k = hf * 32 + j;
    h += in64[w][k] * uw1[k*32 + g];
  }
  h += __shfl_xor(h, 32);
  h = fsilu(h + ub1[g]);
  if (hf == 0) hld[w][g] = h;
  float og = 0.f, ossn = 0.f, oadd = 0.f;
  for (int j = 0; j < 16; ++j) {
    int k = hf * 16 + j;
    float hk = hld[w][k];
    og   += hk * uw2[k*96 +      g];
    ossn += hk * uw2[k*96 + 32 + g];
    oadd += hk * uw2[k*96 + 64 + g];
  }
  og   += __shfl_xor(og, 32);
  ossn += __shfl_xor(ossn, 32);
  oadd += __shfl_xor(oadd, 32);
  og += ub2[g]; ossn += ub2[32 + g]; oadd += ub2[64 + g];
  float s_fin = ns + Vn*Vn*ossn + oadd;
  float vf0 = nv0 + og*Uv0, vf1 = nv1 + og*Uv1, vf2 = nv2 + og*Uv2;
  // ---- readout ----
  if (hf == 0) in64[w][g] = s_fin;
  float h2 = 0.f;
  for (int j = 0; j < 16; ++j) {
    int k = hf * 16 + j;
    h2 += in64[w][k] * rw1[k*32 + g];
  }
  h2 += __shfl_xor(h2, 32);
  h2 = fsilu(h2 + rb1[g]);
  if (hf == 0) hld[w][g] = h2;
  float inv = 0.f, gate = 0.f;
  for (int j = 0; j < 16; ++j) {
    int k = hf * 16 + j;
    float hk = hld[w][k];
    inv  += hk * rw2[k*64 +      g];
    gate += hk * rw2[k*64 + 32 + g];
  }
  inv  += __shfl_xor(inv, 32);
  gate += __shfl_xor(gate, 32);
  inv += rb2[g]; gate += rb2[32 + g];
  if (hf == 0) { vld[w][g*3+0] = vf0; vld[w][g*3+1] = vf1; vld[w][g*3+2] = vf2; }
  float R0 = 0, R1 = 0, R2 = 0;
  for (int j = 0; j < 16; ++j) {
    int f = hf * 16 + j;
    float wv = roV[f*32 + g];
    R0 += vld[w][f*3+0]*wv; R1 += vld[w][f*3+1]*wv; R2 += vld[w][f*3+2]*wv;
  }
  R0 += __shfl_xor(R0, 32); R1 += __shfl_xor(R1, 32); R2 += __shfl_xor(R2, 32);
  if (hf == 0) {
    out[n*32 + g] = inv;
    long eb = (long)N_*32 + n*96 + (long)g*3;
    out[eb+0] = gate*R0; out[eb+1] = gate*R1; out[eb+2] = gate*R2;
  }
}

// ---------------------------------------------------------------------------
extern "C" void kernel_launch(void* const* d_in, const int* in_sizes, int n_in,
                              void* d_out, int out_size, void* d_ws, size_t ws_size,
                              hipStream_t stream)
{
  const float* s_in  = (const float*)d_in[0];
  const float* v_in  = (const float*)d_in[1];   // (N, F, 3)
  const int*   ei    = (const int*)  d_in[2];
  const float* dist  = (const float*)d_in[3];
  const float* edir  = (const float*)d_in[4];
  const float* mp_w1 = (const float*)d_in[5];
  const float* mp_b1 = (const float*)d_in[6];
  const float* mp_w2 = (const float*)d_in[7];
  const float* mp_b2 = (const float*)d_in[8];
  const float* mw_w1 = (const float*)d_in[9];
  const float* mw_b1 = (const float*)d_in[10];
  const float* mw_w2 = (const float*)d_in[11];
  const float* mw_b2 = (const float*)d_in[12];
  const float* u_U   = (const float*)d_in[13];
  const float* u_V   = (const float*)d_in[14];
  const float* u_w1  = (const float*)d_in[15];
  const float* u_b1  = (const float*)d_in[16];
  const float* u_w2  = (const float*)d_in[17];
  const float* u_b2  = (const float*)d_in[18];
  const float* ro_w1 = (const float*)d_in[19];
  const float* ro_b1 = (const float*)d_in[20];
  const float* ro_w2 = (const float*)d_in[21];
  const float* ro_b2 = (const float*)d_in[22];
  const float* ro_V  = (const float*)d_in[23];

  int N_ = in_sizes[0] / 32;
  int E_ = in_sizes[3];

  float*  sB    = (float*)d_ws;                       // N*32
  float*  vB    = sB + (size_t)N_*32;                 // N*96
  float4* Aout4a= (float4*)(vB + (size_t)N_*96);      // N*32 float4
  float4* Aout4b= Aout4a + (size_t)N_*32;             // N*32 float4
  float4* acc4b = Aout4b + (size_t)N_*32;             // N*32 float4
  float4* tbl4a = acc4b + (size_t)N_*32;              // (TBL+1)*32 float4
  float4* tbl4b = tbl4a + (size_t)(TBL+1)*32;         // (TBL+1)*32 float4
  float4* edata = tbl4b + (size_t)(TBL+1)*32;         // E float4
  int*    srcp  = (int*)(edata + (size_t)E_);         // E
  int*    deg   = srcp + E_;                          // N
  int*    off   = deg + N_;                           // N+1
  int*    cursor= off + N_ + 1;                       // N

  // layer-0 acc scratch: d_out (N*32 float4) — dead until final write.
  float4* acc4a = (float4*)d_out;

  int gathBlocks = (N_ + 3) / 4;
  int updBlocks  = (N_ + 3) / 4;
  int edgeBlocks = (E_ + 255) / 256;
  int nodeB32    = (N_ + 31) / 32;
  int tblB32     = (TBL + 1 + 31) / 32;

  // --- CSR hist ---
  hipMemsetAsync(deg, 0, (size_t)N_ * sizeof(int), stream);
  hist_kernel<<<edgeBlocks, 256, 0, stream>>>(ei, deg, E_);

  // --- scan + nodeA(l0) + tbl(l0) + tbl(l1), one launch ---
  scan_prep_kernel<<<1 + nodeB32 + 2*tblB32, 1024, 0, stream>>>(
      deg, off, cursor, N_, s_in,
      mp_w1, mp_b1, mp_w2, mp_b2,
      mw_w1, mw_b1, mw_w2, mw_b2,
      mw_w1 + 1024, mw_b1 + 32, mw_w2 + 4096, mw_b2 + 128,
      Aout4a, tbl4a, tbl4b, nodeB32, tblB32);

  // --- CSR data scatter ---
  scatter_kernel<<<edgeBlocks, 256, 0, stream>>>(ei, dist, edir, cursor, srcp, edata, E_);

  // --- layer 0 ---
  gather_kernel<<<gathBlocks, 256, 0, stream>>>(
      off, srcp, edata, tbl4a, v_in, Aout4a, acc4a, N_);
  update_mid_kernel<<<updBlocks, 256, 0, stream>>>(
      s_in, v_in, acc4a,
      u_U, u_V, u_w1, u_b1, u_w2, u_b2,
      mp_w1 + 1024, mp_b1 + 32, mp_w2 + 4096, mp_b2 + 128,
      sB, vB, Aout4b, N_);

  // --- layer 1 ---
  gather_kernel<<<gathBlocks, 256, 0, stream>>>(
      off, srcp, edata, tbl4b, vB, Aout4b, acc4b, N_);
  update_fin_kernel<<<updBlocks, 256, 0, stream>>>(
      sB, vB, acc4b,
      u_U + 1024, u_V + 1024, u_w1 + 2048, u_b1 + 32, u_w2 + 3072, u_b2 + 96,
      ro_w1, ro_b1, ro_w2, ro_b2, ro_V, (float*)d_out, N_);
}